// Round 6
// baseline (122.586 us; speedup 1.0000x reference)
//
#include <hip/hip_runtime.h>
#include <hip/hip_bf16.h>

// Problem constants (fixed shapes)
#define T_SEQ 1024
#define NBATCH 8
#define NHEAD 12
#define HD 64
#define CDIM 768
#define C3 2304
#define ATT_SCALE 0.125f   // 1/sqrt(64)

typedef __attribute__((ext_vector_type(8))) __bf16 bf16x8;
typedef __attribute__((ext_vector_type(4))) __bf16 bf16x4;
typedef __attribute__((ext_vector_type(2))) __bf16 bf16x2;
typedef __attribute__((ext_vector_type(4))) float  f32x4;

__device__ __forceinline__ f32x4 mfma_bf16(bf16x8 a, bf16x8 b, f32x4 c) {
    return __builtin_amdgcn_mfma_f32_16x16x32_bf16(a, b, c, 0, 0, 0);
}

// async global->LDS, 16B per lane; LDS dest is wave-uniform base (+lane*16 implicit)
__device__ __forceinline__ void gload16(const void* g, void* l) {
    __builtin_amdgcn_global_load_lds(
        (const __attribute__((address_space(1))) unsigned int*)g,
        (__attribute__((address_space(3))) unsigned int*)l, 16, 0, 0);
}

// counted waitcnt — NO sched_barrier (m141: order-pinning defeats the scheduler;
// "memory" clobber still orders all memory ops, which is all we need)
#define WAIT_VM(N)  asm volatile("s_waitcnt vmcnt(" #N ")" ::: "memory")
#define WAIT_LGKM0  asm volatile("s_waitcnt lgkmcnt(0)" ::: "memory")

// ---------------- f32 -> bf16 convert (vectorized) ----------------
__global__ __launch_bounds__(256) void cvt_f32_bf16(const float* __restrict__ in,
                                                    __bf16* __restrict__ out, int n4) {
    int i = blockIdx.x * 256 + threadIdx.x;
    if (i < n4) {
        float4 v = ((const float4*)in)[i];
        bf16x4 o = { (__bf16)v.x, (__bf16)v.y, (__bf16)v.z, (__bf16)v.w };
        ((bf16x4*)out)[i] = o;
    }
}

// ---------------- transpose + convert: W [R][C] f32 -> Wt [C][R] bf16 ----------------
__global__ __launch_bounds__(256) void transpose_cvt(const float* __restrict__ W,
                                                     __bf16* __restrict__ Wt,
                                                     int R, int C) {
    __shared__ float tile[32][33];
    const int c0 = blockIdx.x * 32, r0 = blockIdx.y * 32;
    const int tc = threadIdx.x & 31, tr = threadIdx.x >> 5;   // tr in 0..7
#pragma unroll
    for (int i = 0; i < 4; ++i)
        tile[tr + i * 8][tc] = W[(size_t)(r0 + tr + i * 8) * C + c0 + tc];
    __syncthreads();
#pragma unroll
    for (int i = 0; i < 4; ++i)
        Wt[(size_t)(c0 + tr + i * 8) * R + r0 + tc] = (__bf16)tile[tc][tr + i * 8];
}

// ---------------- QKV GEMM: 256x128 tile, 512 thr (8 waves, 4M x 2N) ----------------
// 3-buffer LDS pipeline, counted vmcnt (3 vmem instr / tile stage -> 6/3/0 waits),
// both-sides XOR chunk-swizzle. Out bf16 + bias. nk >= 3 required (nk = 24).
__global__ __launch_bounds__(512) void gemm_qkv(const __bf16* __restrict__ A,
                                                const __bf16* __restrict__ Bt,
                                                const float* __restrict__ bias,
                                                __bf16* __restrict__ Cout,
                                                int M, int N, int K, int nbx) {
    __shared__ __align__(16) __bf16 sA[3][256 * 32];
    __shared__ __align__(16) __bf16 sB[3][128 * 32];
    const int t = threadIdx.x, l = t & 63, w = t >> 6;
    const int lr = l & 15, lk = l >> 4;
    const int wr = w >> 1, wc = w & 1;                 // 4 x 2 wave grid, 64x64 each
    const int q = gridDim.x >> 3;
    const int swz = (blockIdx.x & 7) * q + (blockIdx.x >> 3);
    const int m0 = (swz / nbx) * 256, n0 = (swz % nbx) * 128;

    // staging: chunk idx -> row r = idx>>2, chunk c = idx&3; fetch global chunk
    // c ^ s(r), s(r) = (r&3)^((r>>2)&3); read side applies the same XOR.
    const int sw_st = ((t >> 2) & 3) ^ ((t >> 4) & 3);
    const int g_off = ((t & 3) ^ sw_st) << 3;
    const int sw_rd = (lr & 3) ^ ((lr >> 2) & 3);

    f32x4 acc[4][4];
#pragma unroll
    for (int m = 0; m < 4; ++m)
#pragma unroll
        for (int n = 0; n < 4; ++n) acc[m][n] = f32x4{0.f, 0.f, 0.f, 0.f};

    const int nk = K >> 5;
    const int rA = t >> 2;            // 0..127 (+ i*128)
    const int rB = t >> 2;            // 0..127

    // prologue: stage tiles 0,1,2 (9 vmem instr in flight per wave)
#pragma unroll
    for (int s = 0; s < 3; ++s) {
        const int k0 = s << 5;
#pragma unroll
        for (int i = 0; i < 2; ++i)
            gload16(A + (size_t)(m0 + i * 128 + rA) * K + k0 + g_off,
                    (char*)&sA[s][0] + (i * 512 + w * 64) * 16);
        gload16(Bt + (size_t)(n0 + rB) * K + k0 + g_off,
                (char*)&sB[s][0] + (w * 64) * 16);
    }

    int cur = 0;
    for (int kt = 0; kt < nk; ++kt) {
        if (kt + 2 < nk)      WAIT_VM(6);
        else if (kt + 1 < nk) WAIT_VM(3);
        else                  WAIT_VM(0);
        __builtin_amdgcn_s_barrier();          // tile kt landed in buf[cur]

        bf16x8 af[4], bg[4];
#pragma unroll
        for (int m = 0; m < 4; ++m)
            af[m] = *(const bf16x8*)(&sA[cur][(wr * 64 + m * 16 + lr) * 32 + ((lk ^ sw_rd) << 3)]);
#pragma unroll
        for (int n = 0; n < 4; ++n)
            bg[n] = *(const bf16x8*)(&sB[cur][(wc * 64 + n * 16 + lr) * 32 + ((lk ^ sw_rd) << 3)]);
        WAIT_LGKM0;                            // fragments in regs; buf[cur] free
        __builtin_amdgcn_s_barrier();          // all waves done reading buf[cur]

        if (kt + 3 < nk) {                     // refill buf[cur] with tile kt+3
            const int k0 = (kt + 3) << 5;
#pragma unroll
            for (int i = 0; i < 2; ++i)
                gload16(A + (size_t)(m0 + i * 128 + rA) * K + k0 + g_off,
                        (char*)&sA[cur][0] + (i * 512 + w * 64) * 16);
            gload16(Bt + (size_t)(n0 + rB) * K + k0 + g_off,
                    (char*)&sB[cur][0] + (w * 64) * 16);
        }

#pragma unroll
        for (int m = 0; m < 4; ++m)
#pragma unroll
            for (int n = 0; n < 4; ++n)
                acc[m][n] = mfma_bf16(af[m], bg[n], acc[m][n]);

        cur = (cur == 2) ? 0 : cur + 1;
    }

#pragma unroll
    for (int n = 0; n < 4; ++n) {
        int col = n0 + wc * 64 + n * 16 + lr;
        float bv = bias[col];
#pragma unroll
        for (int m = 0; m < 4; ++m) {
            int row0 = m0 + wr * 64 + m * 16 + lk * 4;
#pragma unroll
            for (int j = 0; j < 4; ++j)
                Cout[(size_t)(row0 + j) * N + col] = (__bf16)(acc[m][n][j] + bv);
        }
    }
}

// ---------------- proj GEMM: 128x128 tile, 256 thr (as round 5) ----------------
template<int OUT_BF16>
__global__ __launch_bounds__(256) void gemm_bt(const __bf16* __restrict__ A,
                                               const __bf16* __restrict__ Bt,
                                               const float* __restrict__ bias,
                                               void* __restrict__ Cout,
                                               int M, int N, int K, int nbx) {
    __shared__ __align__(16) __bf16 sA[3][128 * 32];
    __shared__ __align__(16) __bf16 sB[3][128 * 32];
    const int t = threadIdx.x, l = t & 63, w = t >> 6;
    const int lr = l & 15, lk = l >> 4;
    const int wr = w >> 1, wc = w & 1;
    const int q = gridDim.x >> 3;
    const int swz = (blockIdx.x & 7) * q + (blockIdx.x >> 3);
    const int m0 = (swz / nbx) * 128, n0 = (swz % nbx) * 128;

    const int sw_st = ((t >> 2) & 3) ^ ((t >> 4) & 3);
    const int g_off = ((t & 3) ^ sw_st) << 3;
    const int sw_rd = (lr & 3) ^ ((lr >> 2) & 3);

    f32x4 acc[4][4];
#pragma unroll
    for (int m = 0; m < 4; ++m)
#pragma unroll
        for (int n = 0; n < 4; ++n) acc[m][n] = f32x4{0.f, 0.f, 0.f, 0.f};

    const int nk = K >> 5;
    const int r_st = t >> 2;

#pragma unroll
    for (int s = 0; s < 3; ++s) {
        const int k0 = s << 5;
#pragma unroll
        for (int i = 0; i < 2; ++i) {
            int r = i * 64 + r_st;
            gload16(A + (size_t)(m0 + r) * K + k0 + g_off,
                    (char*)&sA[s][0] + (i * 256 + w * 64) * 16);
            gload16(Bt + (size_t)(n0 + r) * K + k0 + g_off,
                    (char*)&sB[s][0] + (i * 256 + w * 64) * 16);
        }
    }

    int cur = 0;
    for (int kt = 0; kt < nk; ++kt) {
        if (kt + 2 < nk)      WAIT_VM(8);
        else if (kt + 1 < nk) WAIT_VM(4);
        else                  WAIT_VM(0);
        __builtin_amdgcn_s_barrier();

        bf16x8 af[4], bg[4];
#pragma unroll
        for (int m = 0; m < 4; ++m)
            af[m] = *(const bf16x8*)(&sA[cur][(wr * 64 + m * 16 + lr) * 32 + ((lk ^ sw_rd) << 3)]);
#pragma unroll
        for (int n = 0; n < 4; ++n)
            bg[n] = *(const bf16x8*)(&sB[cur][(wc * 64 + n * 16 + lr) * 32 + ((lk ^ sw_rd) << 3)]);
        WAIT_LGKM0;
        __builtin_amdgcn_s_barrier();

        if (kt + 3 < nk) {
            const int k0 = (kt + 3) << 5;
#pragma unroll
            for (int i = 0; i < 2; ++i) {
                int r = i * 64 + r_st;
                gload16(A + (size_t)(m0 + r) * K + k0 + g_off,
                        (char*)&sA[cur][0] + (i * 256 + w * 64) * 16);
                gload16(Bt + (size_t)(n0 + r) * K + k0 + g_off,
                        (char*)&sB[cur][0] + (i * 256 + w * 64) * 16);
            }
        }

#pragma unroll
        for (int m = 0; m < 4; ++m)
#pragma unroll
            for (int n = 0; n < 4; ++n)
                acc[m][n] = mfma_bf16(af[m], bg[n], acc[m][n]);

        cur = (cur == 2) ? 0 : cur + 1;
    }

#pragma unroll
    for (int n = 0; n < 4; ++n) {
        int col = n0 + wc * 64 + n * 16 + lr;
        float bv = bias[col];
#pragma unroll
        for (int m = 0; m < 4; ++m) {
            int row0 = m0 + wr * 64 + m * 16 + lk * 4;
#pragma unroll
            for (int j = 0; j < 4; ++j) {
                float v = acc[m][n][j] + bv;
                if (OUT_BF16)
                    ((__bf16*)Cout)[(size_t)(row0 + j) * N + col] = (__bf16)v;
                else
                    ((float*)Cout)[(size_t)(row0 + j) * N + col] = v;
            }
        }
    }
}

// ---------------- causal flash attention ----------------
// 768 blocks; block = (pair pr, h, b) handles q-tiles {pr, 15-pr} (uniform 17 tiles).
// 4 waves x 16 q-rows; swapped QK^T (lane owns one q-row -> 2-shuffle softmax).
// K: dbuf LDS via global_load_lds with source-pre-swizzled chunks (linear dest).
// V: dbuf LDS, reg-staged transpose with XOR swizzle. 1 barrier per KV tile.
__global__ __launch_bounds__(256, 2) void attn_fwd(const __bf16* __restrict__ qkv,
                                                   __bf16* __restrict__ y) {
    const int tid = threadIdx.x, l = tid & 63, w = tid >> 6;
    const int lr = l & 15, lk = l >> 4;
    const int r7 = lr & 7;
    const int bid = blockIdx.x;
    const int pr = bid / 96;                 // 0..7
    const int hb = bid % 96;
    const int h = hb % NHEAD;
    const int b = hb / NHEAD;

    __shared__ __align__(16) __bf16 sK[2][64][64];   // chunk-swizzled: phys c = log c ^ (row&7)
    __shared__ __align__(16) __bf16 sV[2][64][64];   // [d][key], XOR-swizzled columns
    __shared__ __align__(16) __bf16 sP[4][16][72];   // per-wave P tile [q][key] (no barrier)

    const size_t baseQ = (size_t)b * T_SEQ * C3 + h * HD;
    const __bf16* Kp = qkv + baseQ + CDIM;
    const __bf16* Vp = qkv + baseQ + 2 * CDIM;

    const int vk0 = tid >> 3;
    const int vc = (tid & 7) << 3;
    const int vg = tid & 7;
    const int krow = tid >> 3;
    const int kchunk = (tid & 7) ^ ((tid >> 3) & 7);

#pragma unroll 1
    for (int job = 0; job < 2; ++job) {
        const int qt = (job == 0) ? pr : 15 - pr;
        const int q0 = qt * 64;
        const int nt = qt + 1;
        const int q_abs = q0 + w * 16 + lr;

        const size_t rowQ = baseQ + (size_t)(q0 + w * 16 + lr) * C3;
        bf16x8 qa0 = *(const bf16x8*)(qkv + rowQ + lk * 8);
        bf16x8 qa1 = *(const bf16x8*)(qkv + rowQ + 32 + lk * 8);

        f32x4 acc[4];
#pragma unroll
        for (int fd = 0; fd < 4; ++fd) acc[fd] = f32x4{0.f, 0.f, 0.f, 0.f};
        float mrun = -1e30f, lrun = 0.f;

        bf16x8 vreg[2];
#pragma unroll
        for (int i = 0; i < 2; ++i)
            vreg[i] = *(const bf16x8*)(Vp + (size_t)(i * 32 + vk0) * C3 + vc);
#pragma unroll
        for (int i = 0; i < 2; ++i)
            gload16(Kp + (size_t)(i * 32 + krow) * C3 + kchunk * 8,
                    (char*)&sK[0][0][0] + (i * 256 + w * 64) * 16);
#pragma unroll
        for (int i = 0; i < 2; ++i) {
            int key = i * 32 + vk0;
#pragma unroll
            for (int e = 0; e < 8; ++e)
                sV[0][vc + e][key ^ ((e ^ vg) << 3)] = vreg[i][e];
        }
        __syncthreads();

#pragma unroll 1
        for (int t = 0; t < nt; ++t) {
            const int kv0 = t * 64;
            const int cur = t & 1, nxt = cur ^ 1;
            const bool pre = (t + 1 < nt);
            if (pre) {
                const int kvp = kv0 + 64;
#pragma unroll
                for (int i = 0; i < 2; ++i)
                    vreg[i] = *(const bf16x8*)(Vp + (size_t)(kvp + i * 32 + vk0) * C3 + vc);
#pragma unroll
                for (int i = 0; i < 2; ++i)
                    gload16(Kp + (size_t)(kvp + i * 32 + krow) * C3 + kchunk * 8,
                            (char*)&sK[nxt][0][0] + (i * 256 + w * 64) * 16);
            }
            // S^T = K·Q^T
            f32x4 s[4];
            __builtin_amdgcn_s_setprio(1);
#pragma unroll
            for (int fc = 0; fc < 4; ++fc) {
                const __bf16* kr = &sK[cur][fc * 16 + lr][0];
                bf16x8 k0 = *(const bf16x8*)(kr + ((lk ^ r7) << 3));
                bf16x8 k1 = *(const bf16x8*)(kr + (((4 + lk) ^ r7) << 3));
                f32x4 z = f32x4{0.f, 0.f, 0.f, 0.f};
                z = mfma_bf16(k0, qa0, z);
                z = mfma_bf16(k1, qa1, z);
                s[fc] = z;
            }
            __builtin_amdgcn_s_setprio(0);
            // online softmax
            float ps[4][4];
#pragma unroll
            for (int fc = 0; fc < 4; ++fc)
#pragma unroll
                for (int j = 0; j < 4; ++j) {
                    int key = kv0 + fc * 16 + lk * 4 + j;
                    ps[fc][j] = (key <= q_abs) ? s[fc][j] * ATT_SCALE : -1e30f;
                }
            float mt = -1e30f;
#pragma unroll
            for (int fc = 0; fc < 4; ++fc)
#pragma unroll
                for (int j = 0; j < 4; ++j) mt = fmaxf(mt, ps[fc][j]);
            mt = fmaxf(mt, __shfl_xor(mt, 16, 64));
            mt = fmaxf(mt, __shfl_xor(mt, 32, 64));
            const float mn = fmaxf(mrun, mt);
            const float corr = __expf(mrun - mn);
            mrun = mn;
            float rs = 0.f;
#pragma unroll
            for (int fc = 0; fc < 4; ++fc)
#pragma unroll
                for (int j = 0; j < 4; ++j) {
                    float p = __expf(ps[fc][j] - mn);
                    ps[fc][j] = p;
                    rs += p;
                }
            rs += __shfl_xor(rs, 16, 64);
            rs += __shfl_xor(rs, 32, 64);
            lrun = lrun * corr + rs;
            float cj[4];
#pragma unroll
            for (int j = 0; j < 4; ++j) cj[j] = __shfl(corr, lk * 4 + j, 64);
#pragma unroll
            for (int fd = 0; fd < 4; ++fd)
#pragma unroll
                for (int j = 0; j < 4; ++j) acc[fd][j] *= cj[j];
            // P -> sP
#pragma unroll
            for (int fc = 0; fc < 4; ++fc)
#pragma unroll
                for (int jp = 0; jp < 2; ++jp) {
                    bf16x2 pk = { (__bf16)ps[fc][jp * 2], (__bf16)ps[fc][jp * 2 + 1] };
                    *(bf16x2*)&sP[w][lr][fc * 16 + lk * 4 + jp * 2] = pk;
                }
            // O += P·V
            __builtin_amdgcn_s_setprio(1);
#pragma unroll
            for (int ks = 0; ks < 2; ++ks) {
                bf16x8 pa = *(const bf16x8*)&sP[w][lr][ks * 32 + lk * 8];
#pragma unroll
                for (int fd = 0; fd < 4; ++fd) {
                    int d = fd * 16 + lr;
                    int sw = ((d & 7) ^ ((d >> 3) & 7)) << 3;
                    bf16x8 vb = *(const bf16x8*)&sV[cur][d][(ks * 32 + lk * 8) ^ sw];
                    acc[fd] = mfma_bf16(pa, vb, acc[fd]);
                }
            }
            __builtin_amdgcn_s_setprio(0);
            if (pre) {
#pragma unroll
                for (int i = 0; i < 2; ++i) {
                    int key = i * 32 + vk0;
#pragma unroll
                    for (int e = 0; e < 8; ++e)
                        sV[nxt][vc + e][key ^ ((e ^ vg) << 3)] = vreg[i][e];
                }
            }
            __syncthreads();
        }

        float linv[4];
#pragma unroll
        for (int j = 0; j < 4; ++j) linv[j] = 1.f / __shfl(lrun, lk * 4 + j, 64);
        const size_t yrow0 = (size_t)(b * T_SEQ + q0 + w * 16 + lk * 4);
#pragma unroll
        for (int fd = 0; fd < 4; ++fd) {
            int col = h * HD + fd * 16 + lr;
#pragma unroll
            for (int j = 0; j < 4; ++j)
                y[(yrow0 + j) * CDIM + col] = (__bf16)(acc[fd][j] * linv[j]);
        }
    }
}

// ---------------- launch ----------------
extern "C" void kernel_launch(void* const* d_in, const int* in_sizes, int n_in,
                              void* d_out, int out_size, void* d_ws, size_t ws_size,
                              hipStream_t stream) {
    const float* x      = (const float*)d_in[0];
    const float* W_attn = (const float*)d_in[1];
    const float* b_attn = (const float*)d_in[2];
    const float* W_proj = (const float*)d_in[3];
    const float* b_proj = (const float*)d_in[4];

    __bf16* xb  = (__bf16*)d_ws;                       // [8192][768]
    __bf16* Wat = xb  + (size_t)8192 * 768;            // [2304][768]  (W_attn^T)
    __bf16* Wpt = Wat + (size_t)2304 * 768;            // [768][768]   (W_proj^T)
    __bf16* qkv = Wpt + (size_t)768 * 768;             // [8192][2304]
    __bf16* yb  = qkv + (size_t)8192 * 2304;           // [8192][768]

    cvt_f32_bf16<<<6144, 256, 0, stream>>>(x, xb, (8192 * 768) / 4);
    transpose_cvt<<<dim3(72, 24), 256, 0, stream>>>(W_attn, Wat, 768, 2304);
    transpose_cvt<<<dim3(24, 24), 256, 0, stream>>>(W_proj, Wpt, 768, 768);

    gemm_qkv<<<32 * 18, 512, 0, stream>>>(xb, Wat, b_attn, qkv, 8192, 2304, 768, 18);
    attn_fwd<<<NBATCH * NHEAD * 8, 256, 0, stream>>>(qkv, yb);
    gemm_bt<0><<<6 * 64, 256, 0, stream>>>(yb, Wpt, b_proj, d_out, 8192, 768, 768, 6);
}

// Round 7
// 119.601 us; speedup vs baseline: 1.0250x; 1.0250x over previous
//
#include <hip/hip_runtime.h>
#include <hip/hip_bf16.h>

// Problem constants (fixed shapes)
#define T_SEQ 1024
#define NBATCH 8
#define NHEAD 12
#define HD 64
#define CDIM 768
#define C3 2304
#define ATT_SCALE 0.125f   // 1/sqrt(64)

typedef __attribute__((ext_vector_type(8))) __bf16 bf16x8;
typedef __attribute__((ext_vector_type(4))) __bf16 bf16x4;
typedef __attribute__((ext_vector_type(2))) __bf16 bf16x2;
typedef __attribute__((ext_vector_type(4))) float  f32x4;

__device__ __forceinline__ f32x4 mfma_bf16(bf16x8 a, bf16x8 b, f32x4 c) {
    return __builtin_amdgcn_mfma_f32_16x16x32_bf16(a, b, c, 0, 0, 0);
}

// async global->LDS, 16B per lane; LDS dest is wave-uniform base (+lane*16 implicit)
__device__ __forceinline__ void gload16(const void* g, void* l) {
    __builtin_amdgcn_global_load_lds(
        (const __attribute__((address_space(1))) unsigned int*)g,
        (__attribute__((address_space(3))) unsigned int*)l, 16, 0, 0);
}

// counted waitcnt — memory clobber orders memory ops; no sched_barrier (m141)
#define WAIT_VM(N)  asm volatile("s_waitcnt vmcnt(" #N ")" ::: "memory")
#define WAIT_LGKM0  asm volatile("s_waitcnt lgkmcnt(0)" ::: "memory")

// ---------------- f32 -> bf16 convert (vectorized) ----------------
__global__ __launch_bounds__(256) void cvt_f32_bf16(const float* __restrict__ in,
                                                    __bf16* __restrict__ out, int n4) {
    int i = blockIdx.x * 256 + threadIdx.x;
    if (i < n4) {
        float4 v = ((const float4*)in)[i];
        bf16x4 o = { (__bf16)v.x, (__bf16)v.y, (__bf16)v.z, (__bf16)v.w };
        ((bf16x4*)out)[i] = o;
    }
}

// ---------------- transpose + convert: W [R][C] f32 -> Wt [C][R] bf16 ----------------
__global__ __launch_bounds__(256) void transpose_cvt(const float* __restrict__ W,
                                                     __bf16* __restrict__ Wt,
                                                     int R, int C) {
    __shared__ float tile[32][33];
    const int c0 = blockIdx.x * 32, r0 = blockIdx.y * 32;
    const int tc = threadIdx.x & 31, tr = threadIdx.x >> 5;   // tr in 0..7
#pragma unroll
    for (int i = 0; i < 4; ++i)
        tile[tr + i * 8][tc] = W[(size_t)(r0 + tr + i * 8) * C + c0 + tc];
    __syncthreads();
#pragma unroll
    for (int i = 0; i < 4; ++i)
        Wt[(size_t)(c0 + tr + i * 8) * R + r0 + tc] = (__bf16)tile[tc][tr + i * 8];
}

// ---------------- GEMM: C[M][N] = A[M][K] @ Bt[N][K]^T + bias ----------------
// 128x128 tile, BK=32, 4 waves; 2-buffer LDS (32KB -> 5 blocks/CU, QKV's 1152
// blocks fully co-resident, no dispatch tail). Counted vmcnt; the read-drain
// (lgkm0+barrier) sits AFTER the MFMAs so the compiler interleaves ds_reads
// with MFMA via fine-grained lgkmcnt — MFMA starts when its first frags land.
template<int OUT_BF16>
__global__ __launch_bounds__(256) void gemm_bt(const __bf16* __restrict__ A,
                                               const __bf16* __restrict__ Bt,
                                               const float* __restrict__ bias,
                                               void* __restrict__ Cout,
                                               int M, int N, int K, int nbx) {
    __shared__ __align__(16) __bf16 sA[2][128 * 32];
    __shared__ __align__(16) __bf16 sB[2][128 * 32];
    const int t = threadIdx.x, l = t & 63, w = t >> 6;
    const int lr = l & 15, lk = l >> 4;
    const int wr = w >> 1, wc = w & 1;
    // XCD swizzle: consecutive swz ids (same XCD) share the A row-panel
    const int q = gridDim.x >> 3;
    const int swz = (blockIdx.x & 7) * q + (blockIdx.x >> 3);
    const int m0 = (swz / nbx) * 128, n0 = (swz % nbx) * 128;

    // staging: idx -> row r=idx>>2, chunk c=idx&3; fetch global chunk c ^ s(r),
    // s(r)=(r&3)^((r>>2)&3); read side applies the same XOR (both-sides swizzle)
    const int r_st = t >> 2;                       // + i*64
    const int sw_st = (r_st & 3) ^ ((r_st >> 2) & 3);
    const int g_off = ((t & 3) ^ sw_st) << 3;
    const int sw_rd = (lr & 3) ^ ((lr >> 2) & 3);

    f32x4 acc[4][4];
#pragma unroll
    for (int m = 0; m < 4; ++m)
#pragma unroll
        for (int n = 0; n < 4; ++n) acc[m][n] = f32x4{0.f, 0.f, 0.f, 0.f};

    const int nk = K >> 5;

    // prologue: stage tiles 0,1 into buffers 0,1 (8 vmem instr in flight)
#pragma unroll
    for (int s = 0; s < 2; ++s) {
        const int k0 = s << 5;
#pragma unroll
        for (int i = 0; i < 2; ++i) {
            int r = i * 64 + r_st;
            gload16(A + (size_t)(m0 + r) * K + k0 + g_off,
                    (char*)&sA[s][0] + (i * 256 + w * 64) * 16);
            gload16(Bt + (size_t)(n0 + r) * K + k0 + g_off,
                    (char*)&sB[s][0] + (i * 256 + w * 64) * 16);
        }
    }

    int cur = 0;
    for (int kt = 0; kt < nk; ++kt) {
        // tile kt's 4 DMAs are the oldest outstanding; allow the younger 4
        if (kt + 1 < nk) WAIT_VM(4);
        else             WAIT_VM(0);
        __builtin_amdgcn_s_barrier();          // tile kt landed in buf[cur]

        bf16x8 af[4], bg[4];
#pragma unroll
        for (int m = 0; m < 4; ++m)
            af[m] = *(const bf16x8*)(&sA[cur][(wr * 64 + m * 16 + lr) * 32 + ((lk ^ sw_rd) << 3)]);
#pragma unroll
        for (int n = 0; n < 4; ++n)
            bg[n] = *(const bf16x8*)(&sB[cur][(wc * 64 + n * 16 + lr) * 32 + ((lk ^ sw_rd) << 3)]);

        // MFMAs issue as fragments arrive (compiler emits fine lgkmcnt waits)
#pragma unroll
        for (int m = 0; m < 4; ++m)
#pragma unroll
            for (int n = 0; n < 4; ++n)
                acc[m][n] = mfma_bf16(af[m], bg[n], acc[m][n]);

        WAIT_LGKM0;                            // my reads done (no-op by now)
        __builtin_amdgcn_s_barrier();          // all waves done reading buf[cur]

        if (kt + 2 < nk) {                     // refill buf[cur] with tile kt+2
            const int k0 = (kt + 2) << 5;
#pragma unroll
            for (int i = 0; i < 2; ++i) {
                int r = i * 64 + r_st;
                gload16(A + (size_t)(m0 + r) * K + k0 + g_off,
                        (char*)&sA[cur][0] + (i * 256 + w * 64) * 16);
                gload16(Bt + (size_t)(n0 + r) * K + k0 + g_off,
                        (char*)&sB[cur][0] + (i * 256 + w * 64) * 16);
            }
        }
        cur ^= 1;
    }

#pragma unroll
    for (int n = 0; n < 4; ++n) {
        int col = n0 + wc * 64 + n * 16 + lr;
        float bv = bias[col];
#pragma unroll
        for (int m = 0; m < 4; ++m) {
            int row0 = m0 + wr * 64 + m * 16 + lk * 4;
#pragma unroll
            for (int j = 0; j < 4; ++j) {
                float v = acc[m][n][j] + bv;
                if (OUT_BF16)
                    ((__bf16*)Cout)[(size_t)(row0 + j) * N + col] = (__bf16)v;
                else
                    ((float*)Cout)[(size_t)(row0 + j) * N + col] = v;
            }
        }
    }
}

// ---------------- causal flash attention (unchanged from round 6) ----------------
__global__ __launch_bounds__(256, 2) void attn_fwd(const __bf16* __restrict__ qkv,
                                                   __bf16* __restrict__ y) {
    const int tid = threadIdx.x, l = tid & 63, w = tid >> 6;
    const int lr = l & 15, lk = l >> 4;
    const int r7 = lr & 7;
    const int bid = blockIdx.x;
    const int pr = bid / 96;                 // 0..7
    const int hb = bid % 96;
    const int h = hb % NHEAD;
    const int b = hb / NHEAD;

    __shared__ __align__(16) __bf16 sK[2][64][64];   // chunk-swizzled: phys c = log c ^ (row&7)
    __shared__ __align__(16) __bf16 sV[2][64][64];   // [d][key], XOR-swizzled columns
    __shared__ __align__(16) __bf16 sP[4][16][72];   // per-wave P tile [q][key] (no barrier)

    const size_t baseQ = (size_t)b * T_SEQ * C3 + h * HD;
    const __bf16* Kp = qkv + baseQ + CDIM;
    const __bf16* Vp = qkv + baseQ + 2 * CDIM;

    const int vk0 = tid >> 3;
    const int vc = (tid & 7) << 3;
    const int vg = tid & 7;
    const int krow = tid >> 3;
    const int kchunk = (tid & 7) ^ ((tid >> 3) & 7);

#pragma unroll 1
    for (int job = 0; job < 2; ++job) {
        const int qt = (job == 0) ? pr : 15 - pr;
        const int q0 = qt * 64;
        const int nt = qt + 1;
        const int q_abs = q0 + w * 16 + lr;

        const size_t rowQ = baseQ + (size_t)(q0 + w * 16 + lr) * C3;
        bf16x8 qa0 = *(const bf16x8*)(qkv + rowQ + lk * 8);
        bf16x8 qa1 = *(const bf16x8*)(qkv + rowQ + 32 + lk * 8);

        f32x4 acc[4];
#pragma unroll
        for (int fd = 0; fd < 4; ++fd) acc[fd] = f32x4{0.f, 0.f, 0.f, 0.f};
        float mrun = -1e30f, lrun = 0.f;

        bf16x8 vreg[2];
#pragma unroll
        for (int i = 0; i < 2; ++i)
            vreg[i] = *(const bf16x8*)(Vp + (size_t)(i * 32 + vk0) * C3 + vc);
#pragma unroll
        for (int i = 0; i < 2; ++i)
            gload16(Kp + (size_t)(i * 32 + krow) * C3 + kchunk * 8,
                    (char*)&sK[0][0][0] + (i * 256 + w * 64) * 16);
#pragma unroll
        for (int i = 0; i < 2; ++i) {
            int key = i * 32 + vk0;
#pragma unroll
            for (int e = 0; e < 8; ++e)
                sV[0][vc + e][key ^ ((e ^ vg) << 3)] = vreg[i][e];
        }
        __syncthreads();

#pragma unroll 1
        for (int t = 0; t < nt; ++t) {
            const int kv0 = t * 64;
            const int cur = t & 1, nxt = cur ^ 1;
            const bool pre = (t + 1 < nt);
            if (pre) {
                const int kvp = kv0 + 64;
#pragma unroll
                for (int i = 0; i < 2; ++i)
                    vreg[i] = *(const bf16x8*)(Vp + (size_t)(kvp + i * 32 + vk0) * C3 + vc);
#pragma unroll
                for (int i = 0; i < 2; ++i)
                    gload16(Kp + (size_t)(kvp + i * 32 + krow) * C3 + kchunk * 8,
                            (char*)&sK[nxt][0][0] + (i * 256 + w * 64) * 16);
            }
            // S^T = K·Q^T
            f32x4 s[4];
            __builtin_amdgcn_s_setprio(1);
#pragma unroll
            for (int fc = 0; fc < 4; ++fc) {
                const __bf16* kr = &sK[cur][fc * 16 + lr][0];
                bf16x8 k0 = *(const bf16x8*)(kr + ((lk ^ r7) << 3));
                bf16x8 k1 = *(const bf16x8*)(kr + (((4 + lk) ^ r7) << 3));
                f32x4 z = f32x4{0.f, 0.f, 0.f, 0.f};
                z = mfma_bf16(k0, qa0, z);
                z = mfma_bf16(k1, qa1, z);
                s[fc] = z;
            }
            __builtin_amdgcn_s_setprio(0);
            // online softmax
            float ps[4][4];
#pragma unroll
            for (int fc = 0; fc < 4; ++fc)
#pragma unroll
                for (int j = 0; j < 4; ++j) {
                    int key = kv0 + fc * 16 + lk * 4 + j;
                    ps[fc][j] = (key <= q_abs) ? s[fc][j] * ATT_SCALE : -1e30f;
                }
            float mt = -1e30f;
#pragma unroll
            for (int fc = 0; fc < 4; ++fc)
#pragma unroll
                for (int j = 0; j < 4; ++j) mt = fmaxf(mt, ps[fc][j]);
            mt = fmaxf(mt, __shfl_xor(mt, 16, 64));
            mt = fmaxf(mt, __shfl_xor(mt, 32, 64));
            const float mn = fmaxf(mrun, mt);
            const float corr = __expf(mrun - mn);
            mrun = mn;
            float rs = 0.f;
#pragma unroll
            for (int fc = 0; fc < 4; ++fc)
#pragma unroll
                for (int j = 0; j < 4; ++j) {
                    float p = __expf(ps[fc][j] - mn);
                    ps[fc][j] = p;
                    rs += p;
                }
            rs += __shfl_xor(rs, 16, 64);
            rs += __shfl_xor(rs, 32, 64);
            lrun = lrun * corr + rs;
            float cj[4];
#pragma unroll
            for (int j = 0; j < 4; ++j) cj[j] = __shfl(corr, lk * 4 + j, 64);
#pragma unroll
            for (int fd = 0; fd < 4; ++fd)
#pragma unroll
                for (int j = 0; j < 4; ++j) acc[fd][j] *= cj[j];
            // P -> sP
#pragma unroll
            for (int fc = 0; fc < 4; ++fc)
#pragma unroll
                for (int jp = 0; jp < 2; ++jp) {
                    bf16x2 pk = { (__bf16)ps[fc][jp * 2], (__bf16)ps[fc][jp * 2 + 1] };
                    *(bf16x2*)&sP[w][lr][fc * 16 + lk * 4 + jp * 2] = pk;
                }
            // O += P·V
            __builtin_amdgcn_s_setprio(1);
#pragma unroll
            for (int ks = 0; ks < 2; ++ks) {
                bf16x8 pa = *(const bf16x8*)&sP[w][lr][ks * 32 + lk * 8];
#pragma unroll
                for (int fd = 0; fd < 4; ++fd) {
                    int d = fd * 16 + lr;
                    int sw = ((d & 7) ^ ((d >> 3) & 7)) << 3;
                    bf16x8 vb = *(const bf16x8*)&sV[cur][d][(ks * 32 + lk * 8) ^ sw];
                    acc[fd] = mfma_bf16(pa, vb, acc[fd]);
                }
            }
            __builtin_amdgcn_s_setprio(0);
            if (pre) {
#pragma unroll
                for (int i = 0; i < 2; ++i) {
                    int key = i * 32 + vk0;
#pragma unroll
                    for (int e = 0; e < 8; ++e)
                        sV[nxt][vc + e][key ^ ((e ^ vg) << 3)] = vreg[i][e];
                }
            }
            __syncthreads();
        }

        float linv[4];
#pragma unroll
        for (int j = 0; j < 4; ++j) linv[j] = 1.f / __shfl(lrun, lk * 4 + j, 64);
        const size_t yrow0 = (size_t)(b * T_SEQ + q0 + w * 16 + lk * 4);
#pragma unroll
        for (int fd = 0; fd < 4; ++fd) {
            int col = h * HD + fd * 16 + lr;
#pragma unroll
            for (int j = 0; j < 4; ++j)
                y[(yrow0 + j) * CDIM + col] = (__bf16)(acc[fd][j] * linv[j]);
        }
    }
}

// ---------------- launch ----------------
extern "C" void kernel_launch(void* const* d_in, const int* in_sizes, int n_in,
                              void* d_out, int out_size, void* d_ws, size_t ws_size,
                              hipStream_t stream) {
    const float* x      = (const float*)d_in[0];
    const float* W_attn = (const float*)d_in[1];
    const float* b_attn = (const float*)d_in[2];
    const float* W_proj = (const float*)d_in[3];
    const float* b_proj = (const float*)d_in[4];

    __bf16* xb  = (__bf16*)d_ws;                       // [8192][768]
    __bf16* Wat = xb  + (size_t)8192 * 768;            // [2304][768]  (W_attn^T)
    __bf16* Wpt = Wat + (size_t)2304 * 768;            // [768][768]   (W_proj^T)
    __bf16* qkv = Wpt + (size_t)768 * 768;             // [8192][2304]
    __bf16* yb  = qkv + (size_t)8192 * 2304;           // [8192][768]

    cvt_f32_bf16<<<6144, 256, 0, stream>>>(x, xb, (8192 * 768) / 4);
    transpose_cvt<<<dim3(72, 24), 256, 0, stream>>>(W_attn, Wat, 768, 2304);
    transpose_cvt<<<dim3(24, 24), 256, 0, stream>>>(W_proj, Wpt, 768, 768);

    gemm_bt<1><<<18 * 64, 256, 0, stream>>>(xb, Wat, b_attn, (void*)qkv, 8192, 2304, 768, 18);
    attn_fwd<<<NBATCH * NHEAD * 8, 256, 0, stream>>>(qkv, yb);
    gemm_bt<0><<<6 * 64, 256, 0, stream>>>(yb, Wpt, b_proj, d_out, 8192, 768, 768, 6);
}

// Round 8
// 118.906 us; speedup vs baseline: 1.0309x; 1.0058x over previous
//
#include <hip/hip_runtime.h>
#include <hip/hip_bf16.h>

// Problem constants (fixed shapes)
#define T_SEQ 1024
#define NBATCH 8
#define NHEAD 12
#define HD 64
#define CDIM 768
#define C3 2304
#define ATT_SCALE 0.125f   // 1/sqrt(64)

typedef __attribute__((ext_vector_type(8))) __bf16 bf16x8;
typedef __attribute__((ext_vector_type(4))) __bf16 bf16x4;
typedef __attribute__((ext_vector_type(2))) __bf16 bf16x2;
typedef __attribute__((ext_vector_type(4))) float  f32x4;
typedef __attribute__((ext_vector_type(16))) float f32x16;

__device__ __forceinline__ f32x4 mfma_bf16(bf16x8 a, bf16x8 b, f32x4 c) {
    return __builtin_amdgcn_mfma_f32_16x16x32_bf16(a, b, c, 0, 0, 0);
}
__device__ __forceinline__ f32x16 mfma32(bf16x8 a, bf16x8 b, f32x16 c) {
    return __builtin_amdgcn_mfma_f32_32x32x16_bf16(a, b, c, 0, 0, 0);
}

// async global->LDS, 16B per lane; LDS dest is wave-uniform base (+lane*16 implicit)
__device__ __forceinline__ void gload16(const void* g, void* l) {
    __builtin_amdgcn_global_load_lds(
        (const __attribute__((address_space(1))) unsigned int*)g,
        (__attribute__((address_space(3))) unsigned int*)l, 16, 0, 0);
}

// counted waitcnt — memory clobber orders memory ops; no sched_barrier (m141)
#define WAIT_VM(N)  asm volatile("s_waitcnt vmcnt(" #N ")" ::: "memory")
#define WAIT_LGKM0  asm volatile("s_waitcnt lgkmcnt(0)" ::: "memory")

// ---------------- f32 -> bf16 convert (vectorized) ----------------
__global__ __launch_bounds__(256) void cvt_f32_bf16(const float* __restrict__ in,
                                                    __bf16* __restrict__ out, int n4) {
    int i = blockIdx.x * 256 + threadIdx.x;
    if (i < n4) {
        float4 v = ((const float4*)in)[i];
        bf16x4 o = { (__bf16)v.x, (__bf16)v.y, (__bf16)v.z, (__bf16)v.w };
        ((bf16x4*)out)[i] = o;
    }
}

// ---------------- transpose + convert: W [R][C] f32 -> Wt [C][R] bf16 ----------------
__global__ __launch_bounds__(256) void transpose_cvt(const float* __restrict__ W,
                                                     __bf16* __restrict__ Wt,
                                                     int R, int C) {
    __shared__ float tile[32][33];
    const int c0 = blockIdx.x * 32, r0 = blockIdx.y * 32;
    const int tc = threadIdx.x & 31, tr = threadIdx.x >> 5;   // tr in 0..7
#pragma unroll
    for (int i = 0; i < 4; ++i)
        tile[tr + i * 8][tc] = W[(size_t)(r0 + tr + i * 8) * C + c0 + tc];
    __syncthreads();
#pragma unroll
    for (int i = 0; i < 4; ++i)
        Wt[(size_t)(c0 + tr + i * 8) * R + r0 + tc] = (__bf16)tile[tc][tr + i * 8];
}

// ---------------- GEMM: C[M][N] = A[M][K] @ Bt[N][K]^T + bias ----------------
// 128x128 tile, BK=32, 4 waves (2x2, wave-tile 64x64 = 2x2 frags of 32x32).
// mfma_f32_32x32x16_bf16 (2382 TF ceiling, half the instruction count of 16x16).
// 3-buffer LDS (48KB, 3 blocks/CU) staging kt+3 (~900cy prefetch distance =
// HBM-miss latency); counted vmcnt (T4, never 0 until tail); MFMAs before the
// read-drain barrier so the compiler interleaves ds_read->MFMA via fine lgkmcnt.
template<int OUT_BF16>
__global__ __launch_bounds__(256) void gemm_bt(const __bf16* __restrict__ A,
                                               const __bf16* __restrict__ Bt,
                                               const float* __restrict__ bias,
                                               void* __restrict__ Cout,
                                               int M, int N, int K, int nbx) {
    __shared__ __align__(16) __bf16 sA[3][128 * 32];
    __shared__ __align__(16) __bf16 sB[3][128 * 32];
    const int t = threadIdx.x, l = t & 63, w = t >> 6;
    const int l31 = l & 31, lh = l >> 5;
    const int wr = w >> 1, wc = w & 1;
    // XCD swizzle: consecutive swz ids (same XCD) share the A row-panel
    const int q = gridDim.x >> 3;
    const int swz = (blockIdx.x & 7) * q + (blockIdx.x >> 3);
    const int m0 = (swz / nbx) * 128, n0 = (swz % nbx) * 128;

    // staging: idx -> row r=idx>>2, chunk c=idx&3 (16B chunks, 4/row at BK=32);
    // fetch global chunk c ^ s(r), s(r)=(r&3)^((r>>2)&3); reads apply same XOR
    const int r_st = t >> 2;                       // + i*64
    const int sw_st = (r_st & 3) ^ ((r_st >> 2) & 3);
    const int g_off = ((t & 3) ^ sw_st) << 3;
    const int sw_rd = (l31 & 3) ^ ((l31 >> 2) & 3);   // frag rows = base + l31

    f32x16 acc[2][2];
#pragma unroll
    for (int m = 0; m < 2; ++m)
#pragma unroll
        for (int n = 0; n < 2; ++n)
#pragma unroll
            for (int r = 0; r < 16; ++r) acc[m][n][r] = 0.f;

    const int nk = K >> 5;

    // prologue: stage tiles 0,1,2 into buffers 0,1,2 (12 vmem instr in flight)
#pragma unroll
    for (int s = 0; s < 3; ++s) {
        const int k0 = s << 5;
#pragma unroll
        for (int i = 0; i < 2; ++i) {
            int r = i * 64 + r_st;
            gload16(A + (size_t)(m0 + r) * K + k0 + g_off,
                    (char*)&sA[s][0] + (i * 256 + w * 64) * 16);
            gload16(Bt + (size_t)(n0 + r) * K + k0 + g_off,
                    (char*)&sB[s][0] + (i * 256 + w * 64) * 16);
        }
    }

    int cur = 0;
    for (int kt = 0; kt < nk; ++kt) {
        // tile kt's 4 DMAs are the oldest outstanding; allow the younger 8
        if (kt + 2 < nk)      WAIT_VM(8);
        else if (kt + 1 < nk) WAIT_VM(4);
        else                  WAIT_VM(0);
        __builtin_amdgcn_s_barrier();          // tile kt landed in buf[cur]

        // fragments: A row = wr*64 + m*32 + l31, k-chunk = (ks*2 + lh) ^ sw_rd
        bf16x8 af[2][2], bg[2][2];
#pragma unroll
        for (int m = 0; m < 2; ++m)
#pragma unroll
            for (int ks = 0; ks < 2; ++ks)
                af[m][ks] = *(const bf16x8*)(&sA[cur][(wr * 64 + m * 32 + l31) * 32
                                                      + ((((ks << 1) | lh) ^ sw_rd) << 3)]);
#pragma unroll
        for (int n = 0; n < 2; ++n)
#pragma unroll
            for (int ks = 0; ks < 2; ++ks)
                bg[n][ks] = *(const bf16x8*)(&sB[cur][(wc * 64 + n * 32 + l31) * 32
                                                      + ((((ks << 1) | lh) ^ sw_rd) << 3)]);

        // 8 MFMAs; compiler interleaves with the ds_reads via fine lgkmcnt
#pragma unroll
        for (int ks = 0; ks < 2; ++ks)
#pragma unroll
            for (int m = 0; m < 2; ++m)
#pragma unroll
                for (int n = 0; n < 2; ++n)
                    acc[m][n] = mfma32(af[m][ks], bg[n][ks], acc[m][n]);

        WAIT_LGKM0;                            // my reads retired
        __builtin_amdgcn_s_barrier();          // all waves done reading buf[cur]

        if (kt + 3 < nk) {                     // refill buf[cur] with tile kt+3
            const int k0 = (kt + 3) << 5;
#pragma unroll
            for (int i = 0; i < 2; ++i) {
                int r = i * 64 + r_st;
                gload16(A + (size_t)(m0 + r) * K + k0 + g_off,
                        (char*)&sA[cur][0] + (i * 256 + w * 64) * 16);
                gload16(Bt + (size_t)(n0 + r) * K + k0 + g_off,
                        (char*)&sB[cur][0] + (i * 256 + w * 64) * 16);
            }
        }
        cur = (cur == 2) ? 0 : cur + 1;
    }

    // epilogue: 32x32 C layout (m74/m101): col = l31, row = (r&3)+8*(r>>2)+4*lh
#pragma unroll
    for (int n = 0; n < 2; ++n) {
        int col = n0 + wc * 64 + n * 32 + l31;
        float bv = bias[col];
#pragma unroll
        for (int m = 0; m < 2; ++m) {
            int rbase = m0 + wr * 64 + m * 32 + 4 * lh;
#pragma unroll
            for (int r = 0; r < 16; ++r) {
                int row = rbase + (r & 3) + 8 * (r >> 2);
                float v = acc[m][n][r] + bv;
                if (OUT_BF16)
                    ((__bf16*)Cout)[(size_t)row * N + col] = (__bf16)v;
                else
                    ((float*)Cout)[(size_t)row * N + col] = v;
            }
        }
    }
}

// ---------------- causal flash attention (unchanged from round 7) ----------------
__global__ __launch_bounds__(256, 2) void attn_fwd(const __bf16* __restrict__ qkv,
                                                   __bf16* __restrict__ y) {
    const int tid = threadIdx.x, l = tid & 63, w = tid >> 6;
    const int lr = l & 15, lk = l >> 4;
    const int r7 = lr & 7;
    const int bid = blockIdx.x;
    const int pr = bid / 96;                 // 0..7
    const int hb = bid % 96;
    const int h = hb % NHEAD;
    const int b = hb / NHEAD;

    __shared__ __align__(16) __bf16 sK[2][64][64];   // chunk-swizzled: phys c = log c ^ (row&7)
    __shared__ __align__(16) __bf16 sV[2][64][64];   // [d][key], XOR-swizzled columns
    __shared__ __align__(16) __bf16 sP[4][16][72];   // per-wave P tile [q][key] (no barrier)

    const size_t baseQ = (size_t)b * T_SEQ * C3 + h * HD;
    const __bf16* Kp = qkv + baseQ + CDIM;
    const __bf16* Vp = qkv + baseQ + 2 * CDIM;

    const int vk0 = tid >> 3;
    const int vc = (tid & 7) << 3;
    const int vg = tid & 7;
    const int krow = tid >> 3;
    const int kchunk = (tid & 7) ^ ((tid >> 3) & 7);

#pragma unroll 1
    for (int job = 0; job < 2; ++job) {
        const int qt = (job == 0) ? pr : 15 - pr;
        const int q0 = qt * 64;
        const int nt = qt + 1;
        const int q_abs = q0 + w * 16 + lr;

        const size_t rowQ = baseQ + (size_t)(q0 + w * 16 + lr) * C3;
        bf16x8 qa0 = *(const bf16x8*)(qkv + rowQ + lk * 8);
        bf16x8 qa1 = *(const bf16x8*)(qkv + rowQ + 32 + lk * 8);

        f32x4 acc[4];
#pragma unroll
        for (int fd = 0; fd < 4; ++fd) acc[fd] = f32x4{0.f, 0.f, 0.f, 0.f};
        float mrun = -1e30f, lrun = 0.f;

        bf16x8 vreg[2];
#pragma unroll
        for (int i = 0; i < 2; ++i)
            vreg[i] = *(const bf16x8*)(Vp + (size_t)(i * 32 + vk0) * C3 + vc);
#pragma unroll
        for (int i = 0; i < 2; ++i)
            gload16(Kp + (size_t)(i * 32 + krow) * C3 + kchunk * 8,
                    (char*)&sK[0][0][0] + (i * 256 + w * 64) * 16);
#pragma unroll
        for (int i = 0; i < 2; ++i) {
            int key = i * 32 + vk0;
#pragma unroll
            for (int e = 0; e < 8; ++e)
                sV[0][vc + e][key ^ ((e ^ vg) << 3)] = vreg[i][e];
        }
        __syncthreads();

#pragma unroll 1
        for (int t = 0; t < nt; ++t) {
            const int kv0 = t * 64;
            const int cur = t & 1, nxt = cur ^ 1;
            const bool pre = (t + 1 < nt);
            if (pre) {
                const int kvp = kv0 + 64;
#pragma unroll
                for (int i = 0; i < 2; ++i)
                    vreg[i] = *(const bf16x8*)(Vp + (size_t)(kvp + i * 32 + vk0) * C3 + vc);
#pragma unroll
                for (int i = 0; i < 2; ++i)
                    gload16(Kp + (size_t)(kvp + i * 32 + krow) * C3 + kchunk * 8,
                            (char*)&sK[nxt][0][0] + (i * 256 + w * 64) * 16);
            }
            // S^T = K·Q^T
            f32x4 s[4];
            __builtin_amdgcn_s_setprio(1);
#pragma unroll
            for (int fc = 0; fc < 4; ++fc) {
                const __bf16* kr = &sK[cur][fc * 16 + lr][0];
                bf16x8 k0 = *(const bf16x8*)(kr + ((lk ^ r7) << 3));
                bf16x8 k1 = *(const bf16x8*)(kr + (((4 + lk) ^ r7) << 3));
                f32x4 z = f32x4{0.f, 0.f, 0.f, 0.f};
                z = mfma_bf16(k0, qa0, z);
                z = mfma_bf16(k1, qa1, z);
                s[fc] = z;
            }
            __builtin_amdgcn_s_setprio(0);
            // online softmax
            float ps[4][4];
#pragma unroll
            for (int fc = 0; fc < 4; ++fc)
#pragma unroll
                for (int j = 0; j < 4; ++j) {
                    int key = kv0 + fc * 16 + lk * 4 + j;
                    ps[fc][j] = (key <= q_abs) ? s[fc][j] * ATT_SCALE : -1e30f;
                }
            float mt = -1e30f;
#pragma unroll
            for (int fc = 0; fc < 4; ++fc)
#pragma unroll
                for (int j = 0; j < 4; ++j) mt = fmaxf(mt, ps[fc][j]);
            mt = fmaxf(mt, __shfl_xor(mt, 16, 64));
            mt = fmaxf(mt, __shfl_xor(mt, 32, 64));
            const float mn = fmaxf(mrun, mt);
            const float corr = __expf(mrun - mn);
            mrun = mn;
            float rs = 0.f;
#pragma unroll
            for (int fc = 0; fc < 4; ++fc)
#pragma unroll
                for (int j = 0; j < 4; ++j) {
                    float p = __expf(ps[fc][j] - mn);
                    ps[fc][j] = p;
                    rs += p;
                }
            rs += __shfl_xor(rs, 16, 64);
            rs += __shfl_xor(rs, 32, 64);
            lrun = lrun * corr + rs;
            float cj[4];
#pragma unroll
            for (int j = 0; j < 4; ++j) cj[j] = __shfl(corr, lk * 4 + j, 64);
#pragma unroll
            for (int fd = 0; fd < 4; ++fd)
#pragma unroll
                for (int j = 0; j < 4; ++j) acc[fd][j] *= cj[j];
            // P -> sP
#pragma unroll
            for (int fc = 0; fc < 4; ++fc)
#pragma unroll
                for (int jp = 0; jp < 2; ++jp) {
                    bf16x2 pk = { (__bf16)ps[fc][jp * 2], (__bf16)ps[fc][jp * 2 + 1] };
                    *(bf16x2*)&sP[w][lr][fc * 16 + lk * 4 + jp * 2] = pk;
                }
            // O += P·V
            __builtin_amdgcn_s_setprio(1);
#pragma unroll
            for (int ks = 0; ks < 2; ++ks) {
                bf16x8 pa = *(const bf16x8*)&sP[w][lr][ks * 32 + lk * 8];
#pragma unroll
                for (int fd = 0; fd < 4; ++fd) {
                    int d = fd * 16 + lr;
                    int sw = ((d & 7) ^ ((d >> 3) & 7)) << 3;
                    bf16x8 vb = *(const bf16x8*)&sV[cur][d][(ks * 32 + lk * 8) ^ sw];
                    acc[fd] = mfma_bf16(pa, vb, acc[fd]);
                }
            }
            __builtin_amdgcn_s_setprio(0);
            if (pre) {
#pragma unroll
                for (int i = 0; i < 2; ++i) {
                    int key = i * 32 + vk0;
#pragma unroll
                    for (int e = 0; e < 8; ++e)
                        sV[nxt][vc + e][key ^ ((e ^ vg) << 3)] = vreg[i][e];
                }
            }
            __syncthreads();
        }

        float linv[4];
#pragma unroll
        for (int j = 0; j < 4; ++j) linv[j] = 1.f / __shfl(lrun, lk * 4 + j, 64);
        const size_t yrow0 = (size_t)(b * T_SEQ + q0 + w * 16 + lk * 4);
#pragma unroll
        for (int fd = 0; fd < 4; ++fd) {
            int col = h * HD + fd * 16 + lr;
#pragma unroll
            for (int j = 0; j < 4; ++j)
                y[(yrow0 + j) * CDIM + col] = (__bf16)(acc[fd][j] * linv[j]);
        }
    }
}

// ---------------- launch ----------------
extern "C" void kernel_launch(void* const* d_in, const int* in_sizes, int n_in,
                              void* d_out, int out_size, void* d_ws, size_t ws_size,
                              hipStream_t stream) {
    const float* x      = (const float*)d_in[0];
    const float* W_attn = (const float*)d_in[1];
    const float* b_attn = (const float*)d_in[2];
    const float* W_proj = (const float*)d_in[3];
    const float* b_proj = (const float*)d_in[4];

    __bf16* xb  = (__bf16*)d_ws;                       // [8192][768]
    __bf16* Wat = xb  + (size_t)8192 * 768;            // [2304][768]  (W_attn^T)
    __bf16* Wpt = Wat + (size_t)2304 * 768;            // [768][768]   (W_proj^T)
    __bf16* qkv = Wpt + (size_t)768 * 768;             // [8192][2304]
    __bf16* yb  = qkv + (size_t)8192 * 2304;           // [8192][768]

    cvt_f32_bf16<<<6144, 256, 0, stream>>>(x, xb, (8192 * 768) / 4);
    transpose_cvt<<<dim3(72, 24), 256, 0, stream>>>(W_attn, Wat, 768, 2304);
    transpose_cvt<<<dim3(24, 24), 256, 0, stream>>>(W_proj, Wpt, 768, 768);

    gemm_bt<1><<<18 * 64, 256, 0, stream>>>(xb, Wat, b_attn, (void*)qkv, 8192, 2304, 768, 18);
    attn_fwd<<<NBATCH * NHEAD * 8, 256, 0, stream>>>(qkv, yb);
    gemm_bt<0><<<6 * 64, 256, 0, stream>>>(yb, Wpt, b_proj, d_out, 8192, 768, 768, 6);
}

// Round 9
// 116.953 us; speedup vs baseline: 1.0482x; 1.0167x over previous
//
#include <hip/hip_runtime.h>
#include <hip/hip_bf16.h>

// Problem constants (fixed shapes)
#define T_SEQ 1024
#define NBATCH 8
#define NHEAD 12
#define HD 64
#define CDIM 768
#define C3 2304
#define ATT_SCALE 0.125f   // 1/sqrt(64)

typedef __attribute__((ext_vector_type(8))) __bf16 bf16x8;
typedef __attribute__((ext_vector_type(4))) __bf16 bf16x4;
typedef __attribute__((ext_vector_type(2))) __bf16 bf16x2;
typedef __attribute__((ext_vector_type(4))) float  f32x4;
typedef __attribute__((ext_vector_type(16))) float f32x16;

__device__ __forceinline__ f32x4 mfma_bf16(bf16x8 a, bf16x8 b, f32x4 c) {
    return __builtin_amdgcn_mfma_f32_16x16x32_bf16(a, b, c, 0, 0, 0);
}
__device__ __forceinline__ f32x16 mfma32(bf16x8 a, bf16x8 b, f32x16 c) {
    return __builtin_amdgcn_mfma_f32_32x32x16_bf16(a, b, c, 0, 0, 0);
}

// async global->LDS, 16B per lane; LDS dest is wave-uniform base (+lane*16 implicit)
__device__ __forceinline__ void gload16(const void* g, void* l) {
    __builtin_amdgcn_global_load_lds(
        (const __attribute__((address_space(1))) unsigned int*)g,
        (__attribute__((address_space(3))) unsigned int*)l, 16, 0, 0);
}

// counted waitcnt — memory clobber orders memory ops; no sched_barrier (m141)
#define WAIT_VM(N)  asm volatile("s_waitcnt vmcnt(" #N ")" ::: "memory")
#define WAIT_LGKM0  asm volatile("s_waitcnt lgkmcnt(0)" ::: "memory")

// ---------------- f32 -> bf16 convert (vectorized) ----------------
__global__ __launch_bounds__(256) void cvt_f32_bf16(const float* __restrict__ in,
                                                    __bf16* __restrict__ out, int n4) {
    int i = blockIdx.x * 256 + threadIdx.x;
    if (i < n4) {
        float4 v = ((const float4*)in)[i];
        bf16x4 o = { (__bf16)v.x, (__bf16)v.y, (__bf16)v.z, (__bf16)v.w };
        ((bf16x4*)out)[i] = o;
    }
}

// ---------------- transpose + convert: W [R][C] f32 -> Wt [C][R] bf16 ----------------
__global__ __launch_bounds__(256) void transpose_cvt(const float* __restrict__ W,
                                                     __bf16* __restrict__ Wt,
                                                     int R, int C) {
    __shared__ float tile[32][33];
    const int c0 = blockIdx.x * 32, r0 = blockIdx.y * 32;
    const int tc = threadIdx.x & 31, tr = threadIdx.x >> 5;   // tr in 0..7
#pragma unroll
    for (int i = 0; i < 4; ++i)
        tile[tr + i * 8][tc] = W[(size_t)(r0 + tr + i * 8) * C + c0 + tc];
    __syncthreads();
#pragma unroll
    for (int i = 0; i < 4; ++i)
        Wt[(size_t)(c0 + tr + i * 8) * R + r0 + tc] = (__bf16)tile[tc][tr + i * 8];
}

// ---------------- GEMM: C[M][N] = A[M][K] @ Bt[N][K]^T + bias ----------------
// 128x128 tile, BK=32, 4 waves (2x2, wave-tile 64x64 = 2x2 frags of 32x32),
// mfma_f32_32x32x16_bf16. 3-buffer LDS, counted vmcnt, MFMAs before read-drain.
// Block->tile mapping (L2 working-set fix): each XCD owns a fixed 8-m-panel
// stripe (A slice 1.6MB, L2-resident) and sweeps n with m-fastest inner order
// (B streams ~2 panels at a time). Requires gridDim.x = 64*nbx (M=8192).
template<int OUT_BF16>
__global__ __launch_bounds__(256) void gemm_bt(const __bf16* __restrict__ A,
                                               const __bf16* __restrict__ Bt,
                                               const float* __restrict__ bias,
                                               void* __restrict__ Cout,
                                               int M, int N, int K, int nbx) {
    __shared__ __align__(16) __bf16 sA[3][128 * 32];
    __shared__ __align__(16) __bf16 sB[3][128 * 32];
    const int t = threadIdx.x, l = t & 63, w = t >> 6;
    const int l31 = l & 31, lh = l >> 5;
    const int wr = w >> 1, wc = w & 1;
    // XCD-stripe mapping: xcd = bid&7 owns m-panels xcd*8..xcd*8+7; within the
    // stripe, m varies fastest (local&7), n advances every 8 blocks.
    const int xcd = blockIdx.x & 7;
    const int local = blockIdx.x >> 3;
    const int m0 = (xcd * 8 + (local & 7)) * 128;
    const int n0 = (local >> 3) * 128;

    // staging: idx -> row r=idx>>2, chunk c=idx&3 (16B chunks, 4/row at BK=32);
    // fetch global chunk c ^ s(r), s(r)=(r&3)^((r>>2)&3); reads apply same XOR
    const int r_st = t >> 2;                       // + i*64
    const int sw_st = (r_st & 3) ^ ((r_st >> 2) & 3);
    const int g_off = ((t & 3) ^ sw_st) << 3;
    const int sw_rd = (l31 & 3) ^ ((l31 >> 2) & 3);   // frag rows = base + l31

    f32x16 acc[2][2];
#pragma unroll
    for (int m = 0; m < 2; ++m)
#pragma unroll
        for (int n = 0; n < 2; ++n)
#pragma unroll
            for (int r = 0; r < 16; ++r) acc[m][n][r] = 0.f;

    const int nk = K >> 5;

    // prologue: stage tiles 0,1,2 into buffers 0,1,2 (12 vmem instr in flight)
#pragma unroll
    for (int s = 0; s < 3; ++s) {
        const int k0 = s << 5;
#pragma unroll
        for (int i = 0; i < 2; ++i) {
            int r = i * 64 + r_st;
            gload16(A + (size_t)(m0 + r) * K + k0 + g_off,
                    (char*)&sA[s][0] + (i * 256 + w * 64) * 16);
            gload16(Bt + (size_t)(n0 + r) * K + k0 + g_off,
                    (char*)&sB[s][0] + (i * 256 + w * 64) * 16);
        }
    }

    int cur = 0;
    for (int kt = 0; kt < nk; ++kt) {
        // tile kt's 4 DMAs are the oldest outstanding; allow the younger 8
        if (kt + 2 < nk)      WAIT_VM(8);
        else if (kt + 1 < nk) WAIT_VM(4);
        else                  WAIT_VM(0);
        __builtin_amdgcn_s_barrier();          // tile kt landed in buf[cur]

        // fragments: A row = wr*64 + m*32 + l31, k-chunk = (ks*2 + lh) ^ sw_rd
        bf16x8 af[2][2], bg[2][2];
#pragma unroll
        for (int m = 0; m < 2; ++m)
#pragma unroll
            for (int ks = 0; ks < 2; ++ks)
                af[m][ks] = *(const bf16x8*)(&sA[cur][(wr * 64 + m * 32 + l31) * 32
                                                      + ((((ks << 1) | lh) ^ sw_rd) << 3)]);
#pragma unroll
        for (int n = 0; n < 2; ++n)
#pragma unroll
            for (int ks = 0; ks < 2; ++ks)
                bg[n][ks] = *(const bf16x8*)(&sB[cur][(wc * 64 + n * 32 + l31) * 32
                                                      + ((((ks << 1) | lh) ^ sw_rd) << 3)]);

        // 8 MFMAs; compiler interleaves with the ds_reads via fine lgkmcnt
#pragma unroll
        for (int ks = 0; ks < 2; ++ks)
#pragma unroll
            for (int m = 0; m < 2; ++m)
#pragma unroll
                for (int n = 0; n < 2; ++n)
                    acc[m][n] = mfma32(af[m][ks], bg[n][ks], acc[m][n]);

        WAIT_LGKM0;                            // my reads retired
        __builtin_amdgcn_s_barrier();          // all waves done reading buf[cur]

        if (kt + 3 < nk) {                     // refill buf[cur] with tile kt+3
            const int k0 = (kt + 3) << 5;
#pragma unroll
            for (int i = 0; i < 2; ++i) {
                int r = i * 64 + r_st;
                gload16(A + (size_t)(m0 + r) * K + k0 + g_off,
                        (char*)&sA[cur][0] + (i * 256 + w * 64) * 16);
                gload16(Bt + (size_t)(n0 + r) * K + k0 + g_off,
                        (char*)&sB[cur][0] + (i * 256 + w * 64) * 16);
            }
        }
        cur = (cur == 2) ? 0 : cur + 1;
    }

    // epilogue: 32x32 C layout (m74/m101): col = l31, row = (r&3)+8*(r>>2)+4*lh
#pragma unroll
    for (int n = 0; n < 2; ++n) {
        int col = n0 + wc * 64 + n * 32 + l31;
        float bv = bias[col];
#pragma unroll
        for (int m = 0; m < 2; ++m) {
            int rbase = m0 + wr * 64 + m * 32 + 4 * lh;
#pragma unroll
            for (int r = 0; r < 16; ++r) {
                int row = rbase + (r & 3) + 8 * (r >> 2);
                float v = acc[m][n][r] + bv;
                if (OUT_BF16)
                    ((__bf16*)Cout)[(size_t)row * N + col] = (__bf16)v;
                else
                    ((float*)Cout)[(size_t)row * N + col] = v;
            }
        }
    }
}

// ---------------- causal flash attention (unchanged from round 8) ----------------
__global__ __launch_bounds__(256, 2) void attn_fwd(const __bf16* __restrict__ qkv,
                                                   __bf16* __restrict__ y) {
    const int tid = threadIdx.x, l = tid & 63, w = tid >> 6;
    const int lr = l & 15, lk = l >> 4;
    const int r7 = lr & 7;
    const int bid = blockIdx.x;
    const int pr = bid / 96;                 // 0..7
    const int hb = bid % 96;
    const int h = hb % NHEAD;
    const int b = hb / NHEAD;

    __shared__ __align__(16) __bf16 sK[2][64][64];   // chunk-swizzled: phys c = log c ^ (row&7)
    __shared__ __align__(16) __bf16 sV[2][64][64];   // [d][key], XOR-swizzled columns
    __shared__ __align__(16) __bf16 sP[4][16][72];   // per-wave P tile [q][key] (no barrier)

    const size_t baseQ = (size_t)b * T_SEQ * C3 + h * HD;
    const __bf16* Kp = qkv + baseQ + CDIM;
    const __bf16* Vp = qkv + baseQ + 2 * CDIM;

    const int vk0 = tid >> 3;
    const int vc = (tid & 7) << 3;
    const int vg = tid & 7;
    const int krow = tid >> 3;
    const int kchunk = (tid & 7) ^ ((tid >> 3) & 7);

#pragma unroll 1
    for (int job = 0; job < 2; ++job) {
        const int qt = (job == 0) ? pr : 15 - pr;
        const int q0 = qt * 64;
        const int nt = qt + 1;
        const int q_abs = q0 + w * 16 + lr;

        const size_t rowQ = baseQ + (size_t)(q0 + w * 16 + lr) * C3;
        bf16x8 qa0 = *(const bf16x8*)(qkv + rowQ + lk * 8);
        bf16x8 qa1 = *(const bf16x8*)(qkv + rowQ + 32 + lk * 8);

        f32x4 acc[4];
#pragma unroll
        for (int fd = 0; fd < 4; ++fd) acc[fd] = f32x4{0.f, 0.f, 0.f, 0.f};
        float mrun = -1e30f, lrun = 0.f;

        bf16x8 vreg[2];
#pragma unroll
        for (int i = 0; i < 2; ++i)
            vreg[i] = *(const bf16x8*)(Vp + (size_t)(i * 32 + vk0) * C3 + vc);
#pragma unroll
        for (int i = 0; i < 2; ++i)
            gload16(Kp + (size_t)(i * 32 + krow) * C3 + kchunk * 8,
                    (char*)&sK[0][0][0] + (i * 256 + w * 64) * 16);
#pragma unroll
        for (int i = 0; i < 2; ++i) {
            int key = i * 32 + vk0;
#pragma unroll
            for (int e = 0; e < 8; ++e)
                sV[0][vc + e][key ^ ((e ^ vg) << 3)] = vreg[i][e];
        }
        __syncthreads();

#pragma unroll 1
        for (int t = 0; t < nt; ++t) {
            const int kv0 = t * 64;
            const int cur = t & 1, nxt = cur ^ 1;
            const bool pre = (t + 1 < nt);
            if (pre) {
                const int kvp = kv0 + 64;
#pragma unroll
                for (int i = 0; i < 2; ++i)
                    vreg[i] = *(const bf16x8*)(Vp + (size_t)(kvp + i * 32 + vk0) * C3 + vc);
#pragma unroll
                for (int i = 0; i < 2; ++i)
                    gload16(Kp + (size_t)(kvp + i * 32 + krow) * C3 + kchunk * 8,
                            (char*)&sK[nxt][0][0] + (i * 256 + w * 64) * 16);
            }
            // S^T = K·Q^T
            f32x4 s[4];
            __builtin_amdgcn_s_setprio(1);
#pragma unroll
            for (int fc = 0; fc < 4; ++fc) {
                const __bf16* kr = &sK[cur][fc * 16 + lr][0];
                bf16x8 k0 = *(const bf16x8*)(kr + ((lk ^ r7) << 3));
                bf16x8 k1 = *(const bf16x8*)(kr + (((4 + lk) ^ r7) << 3));
                f32x4 z = f32x4{0.f, 0.f, 0.f, 0.f};
                z = mfma_bf16(k0, qa0, z);
                z = mfma_bf16(k1, qa1, z);
                s[fc] = z;
            }
            __builtin_amdgcn_s_setprio(0);
            // online softmax
            float ps[4][4];
#pragma unroll
            for (int fc = 0; fc < 4; ++fc)
#pragma unroll
                for (int j = 0; j < 4; ++j) {
                    int key = kv0 + fc * 16 + lk * 4 + j;
                    ps[fc][j] = (key <= q_abs) ? s[fc][j] * ATT_SCALE : -1e30f;
                }
            float mt = -1e30f;
#pragma unroll
            for (int fc = 0; fc < 4; ++fc)
#pragma unroll
                for (int j = 0; j < 4; ++j) mt = fmaxf(mt, ps[fc][j]);
            mt = fmaxf(mt, __shfl_xor(mt, 16, 64));
            mt = fmaxf(mt, __shfl_xor(mt, 32, 64));
            const float mn = fmaxf(mrun, mt);
            const float corr = __expf(mrun - mn);
            mrun = mn;
            float rs = 0.f;
#pragma unroll
            for (int fc = 0; fc < 4; ++fc)
#pragma unroll
                for (int j = 0; j < 4; ++j) {
                    float p = __expf(ps[fc][j] - mn);
                    ps[fc][j] = p;
                    rs += p;
                }
            rs += __shfl_xor(rs, 16, 64);
            rs += __shfl_xor(rs, 32, 64);
            lrun = lrun * corr + rs;
            float cj[4];
#pragma unroll
            for (int j = 0; j < 4; ++j) cj[j] = __shfl(corr, lk * 4 + j, 64);
#pragma unroll
            for (int fd = 0; fd < 4; ++fd)
#pragma unroll
                for (int j = 0; j < 4; ++j) acc[fd][j] *= cj[j];
            // P -> sP
#pragma unroll
            for (int fc = 0; fc < 4; ++fc)
#pragma unroll
                for (int jp = 0; jp < 2; ++jp) {
                    bf16x2 pk = { (__bf16)ps[fc][jp * 2], (__bf16)ps[fc][jp * 2 + 1] };
                    *(bf16x2*)&sP[w][lr][fc * 16 + lk * 4 + jp * 2] = pk;
                }
            // O += P·V
            __builtin_amdgcn_s_setprio(1);
#pragma unroll
            for (int ks = 0; ks < 2; ++ks) {
                bf16x8 pa = *(const bf16x8*)&sP[w][lr][ks * 32 + lk * 8];
#pragma unroll
                for (int fd = 0; fd < 4; ++fd) {
                    int d = fd * 16 + lr;
                    int sw = ((d & 7) ^ ((d >> 3) & 7)) << 3;
                    bf16x8 vb = *(const bf16x8*)&sV[cur][d][(ks * 32 + lk * 8) ^ sw];
                    acc[fd] = mfma_bf16(pa, vb, acc[fd]);
                }
            }
            __builtin_amdgcn_s_setprio(0);
            if (pre) {
#pragma unroll
                for (int i = 0; i < 2; ++i) {
                    int key = i * 32 + vk0;
#pragma unroll
                    for (int e = 0; e < 8; ++e)
                        sV[nxt][vc + e][key ^ ((e ^ vg) << 3)] = vreg[i][e];
                }
            }
            __syncthreads();
        }

        float linv[4];
#pragma unroll
        for (int j = 0; j < 4; ++j) linv[j] = 1.f / __shfl(lrun, lk * 4 + j, 64);
        const size_t yrow0 = (size_t)(b * T_SEQ + q0 + w * 16 + lk * 4);
#pragma unroll
        for (int fd = 0; fd < 4; ++fd) {
            int col = h * HD + fd * 16 + lr;
#pragma unroll
            for (int j = 0; j < 4; ++j)
                y[(yrow0 + j) * CDIM + col] = (__bf16)(acc[fd][j] * linv[j]);
        }
    }
}

// ---------------- launch ----------------
extern "C" void kernel_launch(void* const* d_in, const int* in_sizes, int n_in,
                              void* d_out, int out_size, void* d_ws, size_t ws_size,
                              hipStream_t stream) {
    const float* x      = (const float*)d_in[0];
    const float* W_attn = (const float*)d_in[1];
    const float* b_attn = (const float*)d_in[2];
    const float* W_proj = (const float*)d_in[3];
    const float* b_proj = (const float*)d_in[4];

    __bf16* xb  = (__bf16*)d_ws;                       // [8192][768]
    __bf16* Wat = xb  + (size_t)8192 * 768;            // [2304][768]  (W_attn^T)
    __bf16* Wpt = Wat + (size_t)2304 * 768;            // [768][768]   (W_proj^T)
    __bf16* qkv = Wpt + (size_t)768 * 768;             // [8192][2304]
    __bf16* yb  = qkv + (size_t)8192 * 2304;           // [8192][768]

    cvt_f32_bf16<<<6144, 256, 0, stream>>>(x, xb, (8192 * 768) / 4);
    transpose_cvt<<<dim3(72, 24), 256, 0, stream>>>(W_attn, Wat, 768, 2304);
    transpose_cvt<<<dim3(24, 24), 256, 0, stream>>>(W_proj, Wpt, 768, 768);

    gemm_bt<1><<<18 * 64, 256, 0, stream>>>(xb, Wat, b_attn, (void*)qkv, 8192, 2304, 768, 18);
    attn_fwd<<<NBATCH * NHEAD * 8, 256, 0, stream>>>(qkv, yb);
    gemm_bt<0><<<6 * 64, 256, 0, stream>>>(yb, Wpt, b_proj, d_out, 8192, 768, 768, 6);
}